// Round 7
// baseline (619.953 us; speedup 1.0000x reference)
//
#include <hip/hip_runtime.h>

#define B_   64
#define E_   1024
#define N_   512
#define D_   64
#define HID_ 128
#define T_   5

typedef __bf16 bf16x8 __attribute__((ext_vector_type(8)));
typedef float f32x4 __attribute__((ext_vector_type(4)));

__device__ __forceinline__ unsigned short f2bu(float f) {
    union { float f; unsigned int u; } v; v.f = f;
    unsigned int r = (v.u + 0x7fffu + ((v.u >> 16) & 1u)) >> 16;  // RNE
    return (unsigned short)r;
}

__device__ __forceinline__ unsigned int pack2(float lo, float hi) {
    union { __bf16 b[2]; unsigned int u; } v;
    v.b[0] = (__bf16)lo; v.b[1] = (__bf16)hi;   // RNE
    return v.u;
}

__device__ __forceinline__ uint4 cvt8(float4 a, float4 b) {
    union { __bf16 h[8]; uint4 u; } v;
    v.h[0] = (__bf16)a.x; v.h[1] = (__bf16)a.y; v.h[2] = (__bf16)a.z; v.h[3] = (__bf16)a.w;
    v.h[4] = (__bf16)b.x; v.h[5] = (__bf16)b.y; v.h[6] = (__bf16)b.z; v.h[7] = (__bf16)b.w;
    return v.u;
}

#define MFMA16(a, b, c) __builtin_amdgcn_mfma_f32_16x16x32_bf16((a), (b), (c), 0, 0, 0)

// ---------------------------------------------------------------------------
// Prep: W1[t][d][h] -> W1T[t][h][d] bf16 ; W2[t][h][d] -> W2T[t][d][h] bf16
// ---------------------------------------------------------------------------
__global__ __launch_bounds__(256) void k_prep_w(const float* __restrict__ W1,
                                                const float* __restrict__ W2,
                                                unsigned short* __restrict__ W1T,
                                                unsigned short* __restrict__ W2T) {
    int idx = blockIdx.x * 256 + threadIdx.x;
    if (idx < T_ * HID_ * D_) {
        int t = idx / (HID_ * D_), rem = idx % (HID_ * D_);
        int h = rem / D_, d = rem % D_;
        W1T[idx] = f2bu(W1[(t * D_ + d) * HID_ + h]);
    } else {
        int j = idx - T_ * HID_ * D_;
        int t = j / (D_ * HID_), rem = j % (D_ * HID_);
        int d = rem / HID_, h = rem % HID_;
        W2T[j] = f2bu(W2[(t * HID_ + h) * D_ + d]);
    }
}

// ---------------------------------------------------------------------------
// Prep: ori[b][n][d] -> oriT[b][d][n] bf16; out[b][n][64+d] = ori (fp32);
// NEW: out[b][n][0..64) = 0 (atomic accumulation target for phase 3).
// ---------------------------------------------------------------------------
__global__ __launch_bounds__(256) void k_ori_prep(const float* __restrict__ ori,
                                                  float* __restrict__ out,
                                                  unsigned short* __restrict__ oriT) {
    int b = blockIdx.y, n0 = blockIdx.x * 64;
    __shared__ float tl[64 * 65];
    int tid = threadIdx.x;
    int dl = tid & 63;
    #pragma unroll 4
    for (int p = 0; p < 16; ++p) {
        int nn = p * 4 + (tid >> 6);
        float v = ori[(size_t)(b * N_ + n0 + nn) * D_ + dl];
        out[(size_t)(b * N_ + n0 + nn) * 128 + 64 + dl] = v;
        out[(size_t)(b * N_ + n0 + nn) * 128 + dl] = 0.0f;   // zero agg half
        tl[dl * 65 + nn] = v;
    }
    __syncthreads();
    #pragma unroll 4
    for (int p = 0; p < 16; ++p) {
        int dd = p * 4 + (tid >> 6);
        oriT[(size_t)(b * D_ + dd) * N_ + n0 + dl] = f2bu(tl[dd * 65 + dl]);
    }
}

// ---------------------------------------------------------------------------
// Fused K1+K2+K3, v7:
//   Phase 1: R6's swizzled staging (validated, conflict-free), NO Hbf stores.
//   Phase 2: R0-VERBATIM (best measured phase-2, 88.6us kernel).
//   Epilogue: ef tile (incl. b2 mixture term) -> ef_sh LDS [d][e_loc] instead
//     of global efT (k_gemm_out deleted -> no consumer).
//   Phase 3 (NEW): out[b][n][d] += H_tile^T @ ef_tile via fp32 atomics.
//     K = this block's 64 edges; 8 n-chunks of 64. Staging/MFMA/output
//     indexing is VERBATIM k_gemm_out (verified) with k0 -> e-tile, n0 -> ks.
//     H rows are L2-hot (streamed by this block in phase 1). Cross-block
//     e-reduction = 16 blocks' atomicAdd (device-scope, XCD-safe).
//   LDS: X region 8832 shorts aliases {aA,bB | ef_sh,bB32}; total 67840 B.
// ---------------------------------------------------------------------------
__global__ __launch_bounds__(256) void k_edge_mlp(const float* __restrict__ H,
                                                  const unsigned short* __restrict__ oriT,
                                                  const float* __restrict__ ed,
                                                  const float* __restrict__ b1,
                                                  const float* __restrict__ b2,
                                                  const unsigned short* __restrict__ W1T,
                                                  const unsigned short* __restrict__ W2T,
                                                  float* __restrict__ out) {
    int bx = blockIdx.x;
    int b = bx >> 4, e0 = (bx & 15) * 64;
    // X aliased region: phase1 {aA[0,4096), bB[4096,8192)};
    //                   phase3 {ef_sh[0,4608), bB32 @ short-ofs 4608 (64x33 u32)}
    __shared__ __align__(16) unsigned short X[8832];
    __shared__ __align__(16) unsigned short a_sh[64 * 72];   // edges tile [r][d]
    __shared__ __align__(16) unsigned short w_sh[128 * 72];  // W1T / W2T (aliased)
    __shared__ __align__(16) unsigned short h_sh[64 * 136];  // h' tile [r][hid]
    __shared__ float wd_sh[320];
    __shared__ float b1_sh[640];
    __shared__ float b2_sh[320];
    int tid = threadIdx.x, w = tid >> 6, l = tid & 63, q = l >> 4, c = l & 15;
    int rs = tid >> 3, sgs = tid & 7;
    int swsl = (sgs ^ (rs & 7)) * 8;   // swizzled 8-elem slot; (rs+32)&7 == rs&7

    // small staging (visible by first barrier below)
    for (int u = tid; u < 320; u += 256) wd_sh[u] = ed[((size_t)b * E_ + e0) * T_ + u];
    for (int u = tid; u < 640; u += 256) b1_sh[u] = b1[u];
    for (int u = tid; u < 320; u += 256) b2_sh[u] = b2[u];

    const f32x4 zero = {0.f, 0.f, 0.f, 0.f};

    // ---- Phase 1: edges tile GEMM (M=64 e-rows, N=64 d, K=512 n, BK=64) ----
    f32x4 acc1[4];
    #pragma unroll
    for (int fn = 0; fn < 4; ++fn) acc1[fn] = zero;

    const float* Hb = &H[((size_t)b * E_ + e0) * N_];
    const unsigned short* Ob = &oriT[(size_t)b * D_ * N_];
    unsigned short* aA = X;
    unsigned short* bB = X + 4096;

    for (int ks = 0; ks < 8; ++ks) {
        int k0 = ks * 64;
        const float* s0 = Hb + (size_t)rs * N_ + k0 + sgs * 8;
        const float* s1 = Hb + (size_t)(rs + 32) * N_ + k0 + sgs * 8;
        float4 f00 = *(const float4*)&s0[0], f01 = *(const float4*)&s0[4];
        float4 f10 = *(const float4*)&s1[0], f11 = *(const float4*)&s1[4];
        *(uint4*)&aA[rs * 64 + swsl] = cvt8(f00, f01);
        *(uint4*)&aA[(rs + 32) * 64 + swsl] = cvt8(f10, f11);
        *(uint4*)&bB[rs * 64 + swsl] =
            *(const uint4*)&Ob[(size_t)rs * N_ + k0 + sgs * 8];
        *(uint4*)&bB[(rs + 32) * 64 + swsl] =
            *(const uint4*)&Ob[(size_t)(rs + 32) * N_ + k0 + sgs * 8];
        __syncthreads();
        #pragma unroll
        for (int hh = 0; hh < 2; ++hh) {
            int sl = ((hh * 4 + q) ^ (c & 7)) * 8;
            bf16x8 a0 = *(const bf16x8*)&aA[(w * 16 + c) * 64 + sl];
            #pragma unroll
            for (int fn = 0; fn < 4; ++fn) {
                bf16x8 bb = *(const bf16x8*)&bB[(fn * 16 + c) * 64 + sl];
                acc1[fn] = MFMA16(a0, bb, acc1[fn]);
            }
        }
        __syncthreads();
    }
    // C-layout -> a_sh[r][d] (bf16), same quantization point as R0
    #pragma unroll
    for (int fn = 0; fn < 4; ++fn)
        #pragma unroll
        for (int i = 0; i < 4; ++i)
            a_sh[(w * 16 + q * 4 + i) * 72 + fn * 16 + c] = f2bu(acc1[fn][i]);
    // visibility handled by B0 barrier at top of t-loop

    // ---- Phase 2: per-type MLP + mixture (R0-verbatim) ----
    f32x4 y[4];
    #pragma unroll
    for (int fn = 0; fn < 4; ++fn) y[fn] = zero;

    for (int t = 0; t < T_; ++t) {
        __syncthreads();  // B0: a_sh/wd/b1/b2 visible; prev GEMM2 done with w_sh/h_sh
        #pragma unroll
        for (int p = 0; p < 4; ++p) {  // W1T[t]: 128 rows x 64 bf16 = 1024 uint4
            int u = p * 256 + tid, hh = u >> 3, sg = u & 7;
            *(uint4*)&w_sh[hh * 72 + sg * 8] =
                *(const uint4*)&W1T[(t * HID_ + hh) * D_ + sg * 8];
        }
        __syncthreads();  // B1
        f32x4 hc[8];
        #pragma unroll
        for (int fn = 0; fn < 8; ++fn) hc[fn] = zero;
        #pragma unroll
        for (int ks = 0; ks < 2; ++ks) {
            bf16x8 a = *(const bf16x8*)&a_sh[(w * 16 + c) * 72 + ks * 32 + q * 8];
            #pragma unroll
            for (int fn = 0; fn < 8; ++fn) {
                bf16x8 bb = *(const bf16x8*)&w_sh[(fn * 16 + c) * 72 + ks * 32 + q * 8];
                hc[fn] = MFMA16(a, bb, hc[fn]);
            }
        }
        float wv[4];
        #pragma unroll
        for (int i = 0; i < 4; ++i) wv[i] = wd_sh[(w * 16 + q * 4 + i) * T_ + t];
        #pragma unroll
        for (int fn = 0; fn < 8; ++fn) {
            float b1v = b1_sh[t * HID_ + fn * 16 + c];
            #pragma unroll
            for (int i = 0; i < 4; ++i) {
                float v = hc[fn][i] + b1v;
                v = fmaxf(v, 0.0f) * wv[i];
                h_sh[(w * 16 + q * 4 + i) * 136 + fn * 16 + c] = f2bu(v);
            }
        }
        __syncthreads();  // B2: GEMM1 w_sh reads + h_sh writes complete
        #pragma unroll
        for (int p = 0; p < 4; ++p) {  // W2T[t]: 64 rows x 128 bf16 = 1024 uint4
            int u = p * 256 + tid, dd = u >> 4, sg = u & 15;
            *(uint4*)&w_sh[dd * 136 + sg * 8] =
                *(const uint4*)&W2T[(t * D_ + dd) * HID_ + sg * 8];
        }
        __syncthreads();  // B3
        #pragma unroll
        for (int ks = 0; ks < 4; ++ks) {
            bf16x8 a = *(const bf16x8*)&h_sh[(w * 16 + c) * 136 + ks * 32 + q * 8];
            #pragma unroll
            for (int fn = 0; fn < 4; ++fn) {
                bf16x8 bb = *(const bf16x8*)&w_sh[(fn * 16 + c) * 136 + ks * 32 + q * 8];
                y[fn] = MFMA16(a, bb, y[fn]);
            }
        }
    }

    // epilogue: + sum_t w*b2 -> ef_sh [d][e_loc] bf16 (same values as old efT)
    unsigned short* ef_sh = X;                              // 64 x 72 shorts
    unsigned int* bB32 = (unsigned int*)(X + 4608);         // 64 x 33 u32
    #pragma unroll
    for (int fn = 0; fn < 4; ++fn) {
        int d = fn * 16 + c;
        #pragma unroll
        for (int i = 0; i < 4; ++i) {
            int r = w * 16 + q * 4 + i;
            float s = y[fn][i];
            #pragma unroll
            for (int t = 0; t < T_; ++t) s += wd_sh[r * T_ + t] * b2_sh[t * D_ + d];
            ef_sh[d * 72 + r] = f2bu(s);
        }
    }
    __syncthreads();  // ef_sh visible to all waves (X phase-1 use long done)

    // ---- Phase 3: out[b][n][d] += H_tile^T @ ef_tile (atomic reduction) ----
    // k_gemm_out-verbatim staging/MFMA/output mapping; K = block's 64 edges.
    int r2 = tid >> 3, cg = tid & 7;
    for (int ks = 0; ks < 8; ++ks) {
        int n0 = ks * 64;
        {   // stage H^T chunk [64 n][64 e] pair-packed (L2-hot rows)
            const float* s0 = &H[((size_t)b * E_ + e0 + 2 * r2) * N_ + n0 + cg * 8];
            const float* s1 = s0 + N_;
            float4 f0 = *(const float4*)&s0[0], f1 = *(const float4*)&s0[4];
            float4 g0 = *(const float4*)&s1[0], g1 = *(const float4*)&s1[4];
            float r0a[8] = {f0.x, f0.y, f0.z, f0.w, f1.x, f1.y, f1.z, f1.w};
            float r1a[8] = {g0.x, g0.y, g0.z, g0.w, g1.x, g1.y, g1.z, g1.w};
            #pragma unroll
            for (int j = 0; j < 8; ++j)
                bB32[(cg * 8 + j) * 33 + r2] = pack2(r0a[j], r1a[j]);
        }
        __syncthreads();
        f32x4 acc3[4];
        #pragma unroll
        for (int fm = 0; fm < 4; ++fm) acc3[fm] = zero;
        #pragma unroll
        for (int hh = 0; hh < 2; ++hh) {
            union { unsigned int u[4]; bf16x8 v; } bb;
            #pragma unroll
            for (int i = 0; i < 4; ++i)
                bb.u[i] = bB32[(w * 16 + c) * 33 + hh * 16 + q * 4 + i];
            #pragma unroll
            for (int fm = 0; fm < 4; ++fm) {
                bf16x8 afr = *(const bf16x8*)&ef_sh[(fm * 16 + c) * 72 + hh * 32 + q * 8];
                acc3[fm] = MFMA16(afr, bb.v, acc3[fm]);
            }
        }
        float* op = &out[((size_t)b * N_ + n0 + w * 16 + c) * 128];
        #pragma unroll
        for (int fm = 0; fm < 4; ++fm)
            #pragma unroll
            for (int i = 0; i < 4; ++i)
                atomicAdd(&op[fm * 16 + q * 4 + i], acc3[fm][i]);
        if (ks < 7) __syncthreads();  // bB32 reads done before next stage
    }
}

// ---------------------------------------------------------------------------
extern "C" void kernel_launch(void* const* d_in, const int* in_sizes, int n_in,
                              void* d_out, int out_size, void* d_ws, size_t ws_size,
                              hipStream_t stream) {
    const float* ed  = (const float*)d_in[0];  // [B,E,T]
    const float* H   = (const float*)d_in[1];  // [B,E,N]
    const float* ori = (const float*)d_in[2];  // [B,N,64]
    const float* W1  = (const float*)d_in[3];  // [T,64,128]
    const float* b1  = (const float*)d_in[4];  // [T,128]
    const float* W2  = (const float*)d_in[5];  // [T,128,64]
    const float* b2  = (const float*)d_in[6];  // [T,64]
    float* out = (float*)d_out;

    char* ws = (char*)d_ws;
    size_t used = 0;
    unsigned short* oriT = (unsigned short*)(ws + used); used += (size_t)B_ * D_ * N_ * 2;  // 4 MB
    unsigned short* W1T  = (unsigned short*)(ws + used); used += (size_t)T_ * HID_ * D_ * 2;
    unsigned short* W2T  = (unsigned short*)(ws + used); used += (size_t)T_ * D_ * HID_ * 2;

    hipLaunchKernelGGL(k_prep_w, dim3(320), dim3(256), 0, stream, W1, W2, W1T, W2T);
    hipLaunchKernelGGL(k_ori_prep, dim3(8, 64), dim3(256), 0, stream, ori, out, oriT);
    hipLaunchKernelGGL(k_edge_mlp, dim3(1024), dim3(256), 0, stream,
                       H, oriT, ed, b1, b2, W1T, W2T, out);
}

// Round 8
// 284.089 us; speedup vs baseline: 2.1822x; 2.1822x over previous
//
#include <hip/hip_runtime.h>

#define B_   64
#define E_   1024
#define N_   512
#define D_   64
#define HID_ 128
#define T_   5

typedef __bf16 bf16x8 __attribute__((ext_vector_type(8)));
typedef float f32x4 __attribute__((ext_vector_type(4)));

__device__ __forceinline__ unsigned short f2bu(float f) {
    union { float f; unsigned int u; } v; v.f = f;
    unsigned int r = (v.u + 0x7fffu + ((v.u >> 16) & 1u)) >> 16;  // RNE
    return (unsigned short)r;
}

__device__ __forceinline__ unsigned int pack2(float lo, float hi) {
    union { __bf16 b[2]; unsigned int u; } v;
    v.b[0] = (__bf16)lo; v.b[1] = (__bf16)hi;   // RNE
    return v.u;
}

__device__ __forceinline__ uint4 cvt8(float4 a, float4 b) {
    union { __bf16 h[8]; uint4 u; } v;
    v.h[0] = (__bf16)a.x; v.h[1] = (__bf16)a.y; v.h[2] = (__bf16)a.z; v.h[3] = (__bf16)a.w;
    v.h[4] = (__bf16)b.x; v.h[5] = (__bf16)b.y; v.h[6] = (__bf16)b.z; v.h[7] = (__bf16)b.w;
    return v.u;
}

#define MFMA16(a, b, c) __builtin_amdgcn_mfma_f32_16x16x32_bf16((a), (b), (c), 0, 0, 0)

// ---------------------------------------------------------------------------
// Prep: W1[t][d][h] -> W1T[t][h][d] bf16 ; W2[t][h][d] -> W2T[t][d][h] bf16
// ---------------------------------------------------------------------------
__global__ __launch_bounds__(256) void k_prep_w(const float* __restrict__ W1,
                                                const float* __restrict__ W2,
                                                unsigned short* __restrict__ W1T,
                                                unsigned short* __restrict__ W2T) {
    int idx = blockIdx.x * 256 + threadIdx.x;
    if (idx < T_ * HID_ * D_) {
        int t = idx / (HID_ * D_), rem = idx % (HID_ * D_);
        int h = rem / D_, d = rem % D_;
        W1T[idx] = f2bu(W1[(t * D_ + d) * HID_ + h]);
    } else {
        int j = idx - T_ * HID_ * D_;
        int t = j / (D_ * HID_), rem = j % (D_ * HID_);
        int d = rem / HID_, h = rem % HID_;
        W2T[j] = f2bu(W2[(t * HID_ + h) * D_ + d]);
    }
}

// ---------------------------------------------------------------------------
// Prep: ori[b][n][d] -> oriT[b][d][n] bf16, and out[b][n][64+d] = ori (fp32)
// (R0-verbatim; agg half of out is fully written by k_reduce, no zeroing.)
// ---------------------------------------------------------------------------
__global__ __launch_bounds__(256) void k_ori_prep(const float* __restrict__ ori,
                                                  float* __restrict__ out,
                                                  unsigned short* __restrict__ oriT) {
    int b = blockIdx.y, n0 = blockIdx.x * 64;
    __shared__ float tl[64 * 65];
    int tid = threadIdx.x;
    int dl = tid & 63;
    #pragma unroll 4
    for (int p = 0; p < 16; ++p) {
        int nn = p * 4 + (tid >> 6);
        float v = ori[(size_t)(b * N_ + n0 + nn) * D_ + dl];
        out[(size_t)(b * N_ + n0 + nn) * 128 + 64 + dl] = v;
        tl[dl * 65 + nn] = v;
    }
    __syncthreads();
    #pragma unroll 4
    for (int p = 0; p < 16; ++p) {
        int dd = p * 4 + (tid >> 6);
        oriT[(size_t)(b * D_ + dd) * N_ + n0 + dl] = f2bu(tl[dd * 65 + dl]);
    }
}

// ---------------------------------------------------------------------------
// Fused K1+K2, v8 = R0-VERBATIM with exactly ONE change:
//   phase-1 {aA,bB} (dead after phase 1's trailing barrier) alias phase-2
//   w_sh in region X. LDS 68608 -> 50176 B -> 3 blocks/CU (was 2).
//   No register staging, no barrier changes, no layout changes.
// ---------------------------------------------------------------------------
__global__ __launch_bounds__(256) void k_edge_mlp(const float* __restrict__ H,
                                                  const unsigned short* __restrict__ oriT,
                                                  const float* __restrict__ ed,
                                                  const float* __restrict__ b1,
                                                  const float* __restrict__ b2,
                                                  const unsigned short* __restrict__ W1T,
                                                  const unsigned short* __restrict__ W2T,
                                                  unsigned short* __restrict__ efT) {
    int bx = blockIdx.x;
    int b = bx >> 4, e0 = (bx & 15) * 64;
    // X (9216 shorts = 18432 B):
    //   phase 1: aA = X[0,4608), bB = X[4608,9216)   (64x72 each)
    //   phase 2: w_sh = X[0,9216)                    (128x72 / 64x136)
    __shared__ __align__(16) unsigned short X[9216];
    __shared__ __align__(16) unsigned short a_sh[64 * 72];   // edges tile [r][d]
    __shared__ __align__(16) unsigned short h_sh[64 * 136];  // h' tile [r][hid]
    __shared__ float wd_sh[320];
    __shared__ float b1_sh[640];
    __shared__ float b2_sh[320];
    int tid = threadIdx.x, w = tid >> 6, l = tid & 63, q = l >> 4, c = l & 15;

    // small staging (visible by first barrier below)
    for (int u = tid; u < 320; u += 256) wd_sh[u] = ed[((size_t)b * E_ + e0) * T_ + u];
    for (int u = tid; u < 640; u += 256) b1_sh[u] = b1[u];
    for (int u = tid; u < 320; u += 256) b2_sh[u] = b2[u];

    const f32x4 zero = {0.f, 0.f, 0.f, 0.f};

    // ---- Phase 1: edges tile GEMM (M=64 e-rows, N=64 d, K=512 n, BK=64) ----
    unsigned short* aA = X;
    unsigned short* bB = X + 4608;
    f32x4 acc1[4];
    #pragma unroll
    for (int fn = 0; fn < 4; ++fn) acc1[fn] = zero;

    for (int ks = 0; ks < 8; ++ks) {
        int k0 = ks * 64;
        // stage A: 64 e-rows x 64 floats of H -> bf16 (packed cvt)
        #pragma unroll
        for (int p = 0; p < 2; ++p) {
            int u = p * 256 + tid, r = u >> 3, sg = u & 7;
            const float* s = &H[((size_t)b * E_ + e0 + r) * N_ + k0 + sg * 8];
            float4 f0 = *(const float4*)&s[0];
            float4 f1 = *(const float4*)&s[4];
            *(uint4*)&aA[r * 72 + sg * 8] = cvt8(f0, f1);
        }
        // stage B: oriT rows (bf16, n-contig)
        #pragma unroll
        for (int p = 0; p < 2; ++p) {
            int u = p * 256 + tid, r = u >> 3, sg = u & 7;
            *(uint4*)&bB[r * 72 + sg * 8] =
                *(const uint4*)&oriT[((size_t)b * D_ + r) * N_ + k0 + sg * 8];
        }
        __syncthreads();
        #pragma unroll
        for (int h = 0; h < 2; ++h) {
            bf16x8 a0 = *(const bf16x8*)&aA[(w * 16 + c) * 72 + h * 32 + q * 8];
            #pragma unroll
            for (int fn = 0; fn < 4; ++fn) {
                bf16x8 bb = *(const bf16x8*)&bB[(fn * 16 + c) * 72 + h * 32 + q * 8];
                acc1[fn] = MFMA16(a0, bb, acc1[fn]);
            }
        }
        __syncthreads();   // trailing barrier: phase-1 X reads complete
    }
    // C-layout -> a_sh[r][d] (bf16), same quantization point as R0
    #pragma unroll
    for (int fn = 0; fn < 4; ++fn)
        #pragma unroll
        for (int i = 0; i < 4; ++i)
            a_sh[(w * 16 + q * 4 + i) * 72 + fn * 16 + c] = f2bu(acc1[fn][i]);
    // visibility handled by B0 barrier at top of t-loop

    // ---- Phase 2: per-type MLP + mixture (R0-verbatim; w_sh aliases X) ----
    unsigned short* w_sh = X;
    f32x4 y[4];
    #pragma unroll
    for (int fn = 0; fn < 4; ++fn) y[fn] = zero;

    for (int t = 0; t < T_; ++t) {
        __syncthreads();  // B0: a_sh/wd/b1/b2 visible; prev GEMM2 done with w_sh/h_sh
        #pragma unroll
        for (int p = 0; p < 4; ++p) {  // W1T[t]: 128 rows x 64 bf16 = 1024 uint4
            int u = p * 256 + tid, hh = u >> 3, sg = u & 7;
            *(uint4*)&w_sh[hh * 72 + sg * 8] =
                *(const uint4*)&W1T[(t * HID_ + hh) * D_ + sg * 8];
        }
        __syncthreads();  // B1
        f32x4 hc[8];
        #pragma unroll
        for (int fn = 0; fn < 8; ++fn) hc[fn] = zero;
        #pragma unroll
        for (int ks = 0; ks < 2; ++ks) {
            bf16x8 a = *(const bf16x8*)&a_sh[(w * 16 + c) * 72 + ks * 32 + q * 8];
            #pragma unroll
            for (int fn = 0; fn < 8; ++fn) {
                bf16x8 bb = *(const bf16x8*)&w_sh[(fn * 16 + c) * 72 + ks * 32 + q * 8];
                hc[fn] = MFMA16(a, bb, hc[fn]);
            }
        }
        float wv[4];
        #pragma unroll
        for (int i = 0; i < 4; ++i) wv[i] = wd_sh[(w * 16 + q * 4 + i) * T_ + t];
        #pragma unroll
        for (int fn = 0; fn < 8; ++fn) {
            float b1v = b1_sh[t * HID_ + fn * 16 + c];
            #pragma unroll
            for (int i = 0; i < 4; ++i) {
                float v = hc[fn][i] + b1v;
                v = fmaxf(v, 0.0f) * wv[i];
                h_sh[(w * 16 + q * 4 + i) * 136 + fn * 16 + c] = f2bu(v);
            }
        }
        __syncthreads();  // B2: GEMM1 w_sh reads + h_sh writes complete
        #pragma unroll
        for (int p = 0; p < 4; ++p) {  // W2T[t]: 64 rows x 128 bf16 = 1024 uint4
            int u = p * 256 + tid, dd = u >> 4, sg = u & 15;
            *(uint4*)&w_sh[dd * 136 + sg * 8] =
                *(const uint4*)&W2T[(t * D_ + dd) * HID_ + sg * 8];
        }
        __syncthreads();  // B3
        #pragma unroll
        for (int ks = 0; ks < 4; ++ks) {
            bf16x8 a = *(const bf16x8*)&h_sh[(w * 16 + c) * 136 + ks * 32 + q * 8];
            #pragma unroll
            for (int fn = 0; fn < 4; ++fn) {
                bf16x8 bb = *(const bf16x8*)&w_sh[(fn * 16 + c) * 136 + ks * 32 + q * 8];
                y[fn] = MFMA16(a, bb, y[fn]);
            }
        }
    }
    // epilogue: + sum_t w*b2, write efT[b][d][e] transposed (bf16 ushort4)
    #pragma unroll
    for (int fn = 0; fn < 4; ++fn) {
        int d = fn * 16 + c;
        ushort4 o;
        #pragma unroll
        for (int i = 0; i < 4; ++i) {
            int r = w * 16 + q * 4 + i;
            float s = y[fn][i];
            #pragma unroll
            for (int t = 0; t < T_; ++t) s += wd_sh[r * T_ + t] * b2_sh[t * D_ + d];
            ((unsigned short*)&o)[i] = f2bu(s);
        }
        *(ushort4*)&efT[((size_t)b * D_ + d) * E_ + e0 + w * 16 + q * 4] = o;
    }
}

// ---------------------------------------------------------------------------
// K3, v8: SPLIT-K. Grid 1024 = (b, n-tile, e-half). Each block computes the
// partial sum over its 512 edges (8 K-steps, R4's ping-pong verbatim) and
// writes fp32 partial[kh][b][n][d]. k_reduce sums the two halves into out.
// 4 blocks/CU resident (was 2) -> 2x wave overlap of the latency chains.
// ---------------------------------------------------------------------------
__global__ __launch_bounds__(256) void k_gemm_out(const float* __restrict__ H,
                                                  const unsigned short* __restrict__ efT,
                                                  float* __restrict__ partial) {
    int bid = blockIdx.x;
    int swz = (bid & 7) * 128 + (bid >> 3);   // 1024 % 8 == 0 -> bijective
    int b = swz >> 4, n0 = ((swz >> 1) & 7) * 64, kh = swz & 1;
    int eb = kh * 512;
    __shared__ __align__(16) unsigned short aA[2][64 * 72];   // efT [d][e]
    __shared__ unsigned int bB32[2][64 * 33];                 // H^T [n][e/2] pair-packed
    int tid = threadIdx.x, w = tid >> 6, l = tid & 63, q = l >> 4, c = l & 15;
    int r2 = tid >> 3, cg = tid & 7;
    const f32x4 zero = {0.f, 0.f, 0.f, 0.f};
    f32x4 acc[4];
    #pragma unroll
    for (int fm = 0; fm < 4; ++fm) acc[fm] = zero;

    const unsigned short* Ab = &efT[(size_t)b * D_ * E_ + eb];
    const float* Hb = &H[((size_t)b * E_ + eb) * N_ + n0];

    uint4 ar0, ar1;
    float4 f0, f1, g0, g1;
    {   // prologue: ks=0 loads
        ar0 = *(const uint4*)&Ab[(size_t)r2 * E_ + cg * 8];
        ar1 = *(const uint4*)&Ab[(size_t)(r2 + 32) * E_ + cg * 8];
        const float* s0 = Hb + (size_t)(2 * r2) * N_ + cg * 8;
        const float* s1 = s0 + N_;
        f0 = *(const float4*)&s0[0]; f1 = *(const float4*)&s0[4];
        g0 = *(const float4*)&s1[0]; g1 = *(const float4*)&s1[4];
    }
    {   // write buf0
        *(uint4*)&aA[0][r2 * 72 + cg * 8] = ar0;
        *(uint4*)&aA[0][(r2 + 32) * 72 + cg * 8] = ar1;
        float r0a[8] = {f0.x, f0.y, f0.z, f0.w, f1.x, f1.y, f1.z, f1.w};
        float r1a[8] = {g0.x, g0.y, g0.z, g0.w, g1.x, g1.y, g1.z, g1.w};
        #pragma unroll
        for (int j = 0; j < 8; ++j)
            bB32[0][(cg * 8 + j) * 33 + r2] = pack2(r0a[j], r1a[j]);
    }
    __syncthreads();

    for (int ks = 0; ks < 8; ++ks) {
        if (ks < 7) {  // issue next-step loads before compute
            int k0 = (ks + 1) * 64;
            ar0 = *(const uint4*)&Ab[(size_t)r2 * E_ + k0 + cg * 8];
            ar1 = *(const uint4*)&Ab[(size_t)(r2 + 32) * E_ + k0 + cg * 8];
            const float* s0 = Hb + (size_t)(k0 + 2 * r2) * N_ + cg * 8;
            const float* s1 = s0 + N_;
            f0 = *(const float4*)&s0[0]; f1 = *(const float4*)&s0[4];
        g0 = *(const float4*)&s1[0]; g1 = *(const float4*)&s1[4];
        }
        int cur = ks & 1;
        #pragma unroll
        for (int hh = 0; hh < 2; ++hh) {
            union { unsigned int u[4]; bf16x8 v; } bb;
            #pragma unroll
            for (int i = 0; i < 4; ++i)
                bb.u[i] = bB32[cur][(w * 16 + c) * 33 + hh * 16 + q * 4 + i];
            #pragma unroll
            for (int fm = 0; fm < 4; ++fm) {
                bf16x8 afr = *(const bf16x8*)&aA[cur][(fm * 16 + c) * 72 + hh * 32 + q * 8];
                acc[fm] = MFMA16(afr, bb.v, acc[fm]);
            }
        }
        if (ks < 7) {
            int nxt = cur ^ 1;
            *(uint4*)&aA[nxt][r2 * 72 + cg * 8] = ar0;
            *(uint4*)&aA[nxt][(r2 + 32) * 72 + cg * 8] = ar1;
            float r0a[8] = {f0.x, f0.y, f0.z, f0.w, f1.x, f1.y, f1.z, f1.w};
            float r1a[8] = {g0.x, g0.y, g0.z, g0.w, g1.x, g1.y, g1.z, g1.w};
            #pragma unroll
            for (int j = 0; j < 8; ++j)
                bB32[nxt][(cg * 8 + j) * 33 + r2] = pack2(r0a[j], r1a[j]);
            __syncthreads();
        }
    }
    float* pp = &partial[(((size_t)kh * B_ + b) * N_ + n0 + w * 16 + c) * D_];
    #pragma unroll
    for (int fm = 0; fm < 4; ++fm) {
        *(f32x4*)&pp[fm * 16 + q * 4] = acc[fm];
    }
}

// ---------------------------------------------------------------------------
// K4: out[b][n][0..64) = partial[0][b][n][:] + partial[1][b][n][:]
// 2M fp32 outputs, float4 per thread, grid 2048. ~24 MB traffic, ~5 us.
// ---------------------------------------------------------------------------
__global__ __launch_bounds__(256) void k_reduce(const float* __restrict__ partial,
                                                float* __restrict__ out) {
    int gid = blockIdx.x * 256 + threadIdx.x;   // 524288 threads
    int r = gid >> 4;                            // row index b*N + n
    int dq = (gid & 15) * 4;
    const float* p0 = &partial[(size_t)r * D_ + dq];
    const float* p1 = p0 + (size_t)B_ * N_ * D_;
    float4 a = *(const float4*)p0;
    float4 bb = *(const float4*)p1;
    float4 s = {a.x + bb.x, a.y + bb.y, a.z + bb.z, a.w + bb.w};
    *(float4*)&out[(size_t)r * 128 + dq] = s;
}

// ---------------------------------------------------------------------------
extern "C" void kernel_launch(void* const* d_in, const int* in_sizes, int n_in,
                              void* d_out, int out_size, void* d_ws, size_t ws_size,
                              hipStream_t stream) {
    const float* ed  = (const float*)d_in[0];  // [B,E,T]
    const float* H   = (const float*)d_in[1];  // [B,E,N]
    const float* ori = (const float*)d_in[2];  // [B,N,64]
    const float* W1  = (const float*)d_in[3];  // [T,64,128]
    const float* b1  = (const float*)d_in[4];  // [T,128]
    const float* W2  = (const float*)d_in[5];  // [T,128,64]
    const float* b2  = (const float*)d_in[6];  // [T,64]
    float* out = (float*)d_out;

    char* ws = (char*)d_ws;
    size_t used = 0;
    unsigned short* oriT = (unsigned short*)(ws + used); used += (size_t)B_ * D_ * N_ * 2;   // 4 MB
    unsigned short* W1T  = (unsigned short*)(ws + used); used += (size_t)T_ * HID_ * D_ * 2;
    unsigned short* W2T  = (unsigned short*)(ws + used); used += (size_t)T_ * D_ * HID_ * 2;
    unsigned short* efT  = (unsigned short*)(ws + used); used += (size_t)B_ * D_ * E_ * 2;   // 8 MB
    float* partial = (float*)(ws + used); used += (size_t)2 * B_ * N_ * D_ * 4;              // 16 MB

    hipLaunchKernelGGL(k_prep_w, dim3(320), dim3(256), 0, stream, W1, W2, W1T, W2T);
    hipLaunchKernelGGL(k_ori_prep, dim3(8, 64), dim3(256), 0, stream, ori, out, oriT);
    hipLaunchKernelGGL(k_edge_mlp, dim3(1024), dim3(256), 0, stream,
                       H, oriT, ed, b1, b2, W1T, W2T, efT);
    hipLaunchKernelGGL(k_gemm_out, dim3(1024), dim3(256), 0, stream, H, efT, partial);
    hipLaunchKernelGGL(k_reduce, dim3(2048), dim3(256), 0, stream, partial, out);
}

// Round 10
// 266.449 us; speedup vs baseline: 2.3267x; 1.0662x over previous
//
#include <hip/hip_runtime.h>

#define B_   64
#define E_   1024
#define N_   512
#define D_   64
#define HID_ 128
#define T_   5

typedef __bf16 bf16x8 __attribute__((ext_vector_type(8)));
typedef float f32x4 __attribute__((ext_vector_type(4)));

__device__ __forceinline__ unsigned short f2bu(float f) {
    union { float f; unsigned int u; } v; v.f = f;
    unsigned int r = (v.u + 0x7fffu + ((v.u >> 16) & 1u)) >> 16;  // RNE
    return (unsigned short)r;
}

__device__ __forceinline__ unsigned int pack2(float lo, float hi) {
    union { __bf16 b[2]; unsigned int u; } v;
    v.b[0] = (__bf16)lo; v.b[1] = (__bf16)hi;   // RNE
    return v.u;
}

__device__ __forceinline__ uint4 cvt8(float4 a, float4 b) {
    union { __bf16 h[8]; uint4 u; } v;
    v.h[0] = (__bf16)a.x; v.h[1] = (__bf16)a.y; v.h[2] = (__bf16)a.z; v.h[3] = (__bf16)a.w;
    v.h[4] = (__bf16)b.x; v.h[5] = (__bf16)b.y; v.h[6] = (__bf16)b.z; v.h[7] = (__bf16)b.w;
    return v.u;
}

#define MFMA16(a, b, c) __builtin_amdgcn_mfma_f32_16x16x32_bf16((a), (b), (c), 0, 0, 0)

// Raw barrier: LDS-visibility only, NO vmcnt drain — in-flight global loads
// survive. sched_barrier(0) pins emission order around the barrier point.
#define RBAR() do {                                          \
    __builtin_amdgcn_sched_barrier(0);                       \
    asm volatile("s_waitcnt lgkmcnt(0)" ::: "memory");       \
    __builtin_amdgcn_s_barrier();                            \
    __builtin_amdgcn_sched_barrier(0);                       \
} while (0)

// ---------------------------------------------------------------------------
// Prep: W1[t][d][h] -> W1T[t][h][d] bf16 ; W2[t][h][d] -> W2T[t][d][h] bf16
// ---------------------------------------------------------------------------
__global__ __launch_bounds__(256) void k_prep_w(const float* __restrict__ W1,
                                                const float* __restrict__ W2,
                                                unsigned short* __restrict__ W1T,
                                                unsigned short* __restrict__ W2T) {
    int idx = blockIdx.x * 256 + threadIdx.x;
    if (idx < T_ * HID_ * D_) {
        int t = idx / (HID_ * D_), rem = idx % (HID_ * D_);
        int h = rem / D_, d = rem % D_;
        W1T[idx] = f2bu(W1[(t * D_ + d) * HID_ + h]);
    } else {
        int j = idx - T_ * HID_ * D_;
        int t = j / (D_ * HID_), rem = j % (D_ * HID_);
        int d = rem / HID_, h = rem % HID_;
        W2T[j] = f2bu(W2[(t * HID_ + h) * D_ + d]);
    }
}

// ---------------------------------------------------------------------------
// Prep: ori[b][n][d] -> oriT[b][d][n] bf16, and out[b][n][64+d] = ori (fp32)
// ---------------------------------------------------------------------------
__global__ __launch_bounds__(256) void k_ori_prep(const float* __restrict__ ori,
                                                  float* __restrict__ out,
                                                  unsigned short* __restrict__ oriT) {
    int b = blockIdx.y, n0 = blockIdx.x * 64;
    __shared__ float tl[64 * 65];
    int tid = threadIdx.x;
    int dl = tid & 63;
    #pragma unroll 4
    for (int p = 0; p < 16; ++p) {
        int nn = p * 4 + (tid >> 6);
        float v = ori[(size_t)(b * N_ + n0 + nn) * D_ + dl];
        out[(size_t)(b * N_ + n0 + nn) * 128 + 64 + dl] = v;
        tl[dl * 65 + nn] = v;
    }
    __syncthreads();
    #pragma unroll 4
    for (int p = 0; p < 16; ++p) {
        int dd = p * 4 + (tid >> 6);
        oriT[(size_t)(b * D_ + dd) * N_ + n0 + dl] = f2bu(tl[dd * 65 + dl]);
    }
}

// ---------------------------------------------------------------------------
// Fused K1+K2, v9 (resubmit — R9 was a container-infra failure; audit found
// no hang/fault path: all barriers block-uniform, swizzle algebra verified,
// no OOB). Counted-vmcnt pipeline (guide T3/T4 pattern):
//   ALL barriers are raw {lgkmcnt(0); s_barrier} — no vmcnt drain, so global
//   loads issued before a barrier stay in flight across it.
//   Phase 1: ping-pong, 1 raw barrier/step. Phase 2: split w1/w2 buffers,
//   t+1 weight prefetch under the GEMMs, 2 raw barriers/t.
//   Intervals: 36 -> 19, none with a full drain.
// ---------------------------------------------------------------------------
__global__ __launch_bounds__(256, 2) void k_edge_mlp(const float* __restrict__ H,
                                                     const unsigned short* __restrict__ oriT,
                                                     const float* __restrict__ ed,
                                                     const float* __restrict__ b1,
                                                     const float* __restrict__ b2,
                                                     const unsigned short* __restrict__ W1T,
                                                     const unsigned short* __restrict__ W2T,
                                                     unsigned short* __restrict__ efT) {
    int bx = blockIdx.x;
    int b = bx >> 4, e0 = (bx & 15) * 64;
    // X (16384 shorts = 32 KB):
    //   phase 1: buf0 {aA@0, bB@4096}, buf1 {aA@8192, bB@12288}  (64x64 each)
    //   phase 2: w1_sh = X[0,8192) (128x64 swz), w2_sh = X[8192,16384) (64x128 swz)
    __shared__ __align__(16) unsigned short X[16384];
    __shared__ __align__(16) unsigned short a_sh[64 * 64];   // wave-own, swizzled
    __shared__ __align__(16) unsigned short h_sh[64 * 128];  // wave-own, swizzled
    __shared__ float wd_sh[320];
    __shared__ float b1_sh[640];
    __shared__ float b2_sh[320];
    int tid = threadIdx.x, w = tid >> 6, l = tid & 63, q = l >> 4, c = l & 15;
    int rs = tid >> 3, sgs = tid & 7;
    int swsl = (sgs ^ (rs & 7)) * 8;          // swizzled slot; (rs+32)&7 == rs&7

    // small staging (visible by the first RBAR below)
    for (int u = tid; u < 320; u += 256) wd_sh[u] = ed[((size_t)b * E_ + e0) * T_ + u];
    for (int u = tid; u < 640; u += 256) b1_sh[u] = b1[u];
    for (int u = tid; u < 320; u += 256) b2_sh[u] = b2[u];

    const f32x4 zero = {0.f, 0.f, 0.f, 0.f};

    // ---- Phase 1: edges tile GEMM (M=64 e, N=64 d, K=512 n, BK=64) ----
    f32x4 acc1[4];
    #pragma unroll
    for (int fn = 0; fn < 4; ++fn) acc1[fn] = zero;

    const float* Hb = &H[((size_t)b * E_ + e0) * N_];
    const unsigned short* Ob = &oriT[(size_t)b * D_ * N_];

    float4 f00, f01, f10, f11;
    uint4 ob0, ob1;
    uint4 wr1[4], wr2[4];   // phase-2 weight prefetch registers

    {   // prologue: ks=0 loads
        const float* s0 = Hb + (size_t)rs * N_ + sgs * 8;
        const float* s1 = Hb + (size_t)(rs + 32) * N_ + sgs * 8;
        f00 = *(const float4*)&s0[0]; f01 = *(const float4*)&s0[4];
        f10 = *(const float4*)&s1[0]; f11 = *(const float4*)&s1[4];
        ob0 = *(const uint4*)&Ob[(size_t)rs * N_ + sgs * 8];
        ob1 = *(const uint4*)&Ob[(size_t)(rs + 32) * N_ + sgs * 8];
    }
    {   // write buf0 (swizzled)
        unsigned short* aA = X;
        unsigned short* bB = X + 4096;
        *(uint4*)&aA[rs * 64 + swsl] = cvt8(f00, f01);
        *(uint4*)&aA[(rs + 32) * 64 + swsl] = cvt8(f10, f11);
        *(uint4*)&bB[rs * 64 + swsl] = ob0;
        *(uint4*)&bB[(rs + 32) * 64 + swsl] = ob1;
    }
    RBAR();

    #pragma unroll
    for (int ks = 0; ks < 8; ++ks) {
        if (ks < 7) {  // issue next-step loads; they fly across the RBAR below
            int k0 = (ks + 1) * 64;
            const float* s0 = Hb + (size_t)rs * N_ + k0 + sgs * 8;
            const float* s1 = Hb + (size_t)(rs + 32) * N_ + k0 + sgs * 8;
            f00 = *(const float4*)&s0[0]; f01 = *(const float4*)&s0[4];
            f10 = *(const float4*)&s1[0]; f11 = *(const float4*)&s1[4];
            ob0 = *(const uint4*)&Ob[(size_t)rs * N_ + k0 + sgs * 8];
            ob1 = *(const uint4*)&Ob[(size_t)(rs + 32) * N_ + k0 + sgs * 8];
        }
        if (ks == 7) {  // issue t=0 weight loads; fly during last compute
            #pragma unroll
            for (int p = 0; p < 4; ++p) {
                int u2 = p * 256 + tid;
                wr1[p] = *(const uint4*)&W1T[(size_t)(u2 >> 3) * D_ + (u2 & 7) * 8];
                wr2[p] = *(const uint4*)&W2T[(size_t)(u2 >> 4) * HID_ + (u2 & 15) * 8];
            }
        }
        const unsigned short* aA = X + (ks & 1) * 8192;
        const unsigned short* bB = aA + 4096;
        #pragma unroll
        for (int hh = 0; hh < 2; ++hh) {
            int sl = ((hh * 4 + q) ^ (c & 7)) * 8;
            bf16x8 a0 = *(const bf16x8*)&aA[(w * 16 + c) * 64 + sl];
            #pragma unroll
            for (int fn = 0; fn < 4; ++fn) {
                bf16x8 bb = *(const bf16x8*)&bB[(fn * 16 + c) * 64 + sl];
                acc1[fn] = MFMA16(a0, bb, acc1[fn]);
            }
        }
        if (ks < 7) {
            unsigned short* aN = X + ((ks & 1) ^ 1) * 8192;
            unsigned short* bN = aN + 4096;
            *(uint4*)&aN[rs * 64 + swsl] = cvt8(f00, f01);
            *(uint4*)&aN[(rs + 32) * 64 + swsl] = cvt8(f10, f11);
            *(uint4*)&bN[rs * 64 + swsl] = ob0;
            *(uint4*)&bN[(rs + 32) * 64 + swsl] = ob1;
            RBAR();
        }
    }

    // a_sh: wave-own rows, swizzled (write rows w*16+q*4+i, read rows w*16+c)
    #pragma unroll
    for (int fn = 0; fn < 4; ++fn)
        #pragma unroll
        for (int i = 0; i < 4; ++i) {
            int row = w * 16 + q * 4 + i;
            a_sh[row * 64 + ((fn * 16 + c) ^ ((row & 7) << 3))] = f2bu(acc1[fn][i]);
        }
    // A-fragments for GEMM1 (t-invariant), intra-wave read
    bf16x8 afr[2];
    #pragma unroll
    for (int ks2 = 0; ks2 < 2; ++ks2)
        afr[ks2] = *(const bf16x8*)&a_sh[(w * 16 + c) * 64 + (((ks2 * 4 + q) ^ (c & 7)) * 8)];

    RBAR();  // all waves done reading X (ks=7) before weight writes

    unsigned short* w1_sh = X;            // 128 x 64 swz
    unsigned short* w2_sh = X + 8192;     // 64 x 128 swz

    // ---- Phase 2: per-type MLP + mixture (2 raw barriers per t) ----
    f32x4 y[4];
    #pragma unroll
    for (int fn = 0; fn < 4; ++fn) y[fn] = zero;

    #pragma unroll
    for (int t = 0; t < T_; ++t) {
        // write weights t from prefetch regs (compiler inserts counted vmcnt)
        #pragma unroll
        for (int p = 0; p < 4; ++p) {
            int u2 = p * 256 + tid, hh = u2 >> 3, sg = u2 & 7;
            *(uint4*)&w1_sh[hh * 64 + ((sg ^ (hh & 7)) * 8)] = wr1[p];
        }
        #pragma unroll
        for (int p = 0; p < 4; ++p) {
            int u2 = p * 256 + tid, dd = u2 >> 4, sg = u2 & 15;
            *(uint4*)&w2_sh[dd * 128 + ((sg ^ (dd & 7)) * 8)] = wr2[p];
        }
        RBAR();  // B1: weights visible
        if (t < T_ - 1) {  // prefetch t+1 weights; latency hides under GEMMs
            #pragma unroll
            for (int p = 0; p < 4; ++p) {
                int u2 = p * 256 + tid;
                wr1[p] = *(const uint4*)&W1T[((size_t)(t + 1) * HID_ + (u2 >> 3)) * D_ + (u2 & 7) * 8];
                wr2[p] = *(const uint4*)&W2T[((size_t)(t + 1) * D_ + (u2 >> 4)) * HID_ + (u2 & 15) * 8];
            }
        }
        f32x4 hc[8];
        #pragma unroll
        for (int fn = 0; fn < 8; ++fn) hc[fn] = zero;
        #pragma unroll
        for (int ks2 = 0; ks2 < 2; ++ks2) {
            #pragma unroll
            for (int fn = 0; fn < 8; ++fn) {
                bf16x8 bb = *(const bf16x8*)&w1_sh[(fn * 16 + c) * 64 + (((ks2 * 4 + q) ^ (c & 7)) * 8)];
                hc[fn] = MFMA16(afr[ks2], bb, hc[fn]);
            }
        }
        float wv[4];
        #pragma unroll
        for (int i = 0; i < 4; ++i) wv[i] = wd_sh[(w * 16 + q * 4 + i) * T_ + t];
        #pragma unroll
        for (int fn = 0; fn < 8; ++fn) {
            float b1v = b1_sh[t * HID_ + fn * 16 + c];
            #pragma unroll
            for (int i = 0; i < 4; ++i) {
                float v = hc[fn][i] + b1v;
                v = fmaxf(v, 0.0f) * wv[i];
                int row = q * 4 + i;
                h_sh[(w * 16 + row) * 128 + ((fn * 16 + c) ^ ((row & 7) << 3))] = f2bu(v);
            }
        }
        // h_sh: wave-own write->read (rows w*16+*), intra-wave DS ordering
        #pragma unroll
        for (int ks2 = 0; ks2 < 4; ++ks2) {
            bf16x8 a = *(const bf16x8*)&h_sh[(w * 16 + c) * 128 + (((ks2 * 4 + q) ^ (c & 7)) * 8)];
            #pragma unroll
            for (int fn = 0; fn < 4; ++fn) {
                bf16x8 bb = *(const bf16x8*)&w2_sh[(fn * 16 + c) * 128 + (((ks2 * 4 + q) ^ (c & 7)) * 8)];
                y[fn] = MFMA16(a, bb, y[fn]);
            }
        }
        RBAR();  // B2: all waves' w1/w2 reads done before next t's writes
    }

    // epilogue: + sum_t w*b2, write efT[b][d][e] transposed (bf16 ushort4)
    #pragma unroll
    for (int fn = 0; fn < 4; ++fn) {
        int d = fn * 16 + c;
        ushort4 o;
        #pragma unroll
        for (int i = 0; i < 4; ++i) {
            int r = w * 16 + q * 4 + i;
            float s = y[fn][i];
            #pragma unroll
            for (int t = 0; t < T_; ++t) s += wd_sh[r * T_ + t] * b2_sh[t * D_ + d];
            ((unsigned short*)&o)[i] = f2bu(s);
        }
        *(ushort4*)&efT[((size_t)b * D_ + d) * E_ + e0 + w * 16 + q * 4] = o;
    }
}

// ---------------------------------------------------------------------------
// K3: out[b][n][d] = sum_e H[b][e][n] * ef[b][e][d] as outT tile.
// R4-VERBATIM (measured ~16us by R7-decomposition — leave it alone).
// ---------------------------------------------------------------------------
__global__ __launch_bounds__(256) void k_gemm_out(const float* __restrict__ H,
                                                  const unsigned short* __restrict__ efT,
                                                  float* __restrict__ out) {
    int bid = blockIdx.x;
    int swz = (bid & 7) * 64 + (bid >> 3);    // 512 % 8 == 0 -> bijective
    int b = swz >> 3, n0 = (swz & 7) * 64;
    __shared__ __align__(16) unsigned short aA[2][64 * 72];   // efT [d][e]
    __shared__ unsigned int bB32[2][64 * 33];                 // H^T [n][e/2] pair-packed
    int tid = threadIdx.x, w = tid >> 6, l = tid & 63, q = l >> 4, c = l & 15;
    int r2 = tid >> 3, cg = tid & 7;
    const f32x4 zero = {0.f, 0.f, 0.f, 0.f};
    f32x4 acc[4];
    #pragma unroll
    for (int fm = 0; fm < 4; ++fm) acc[fm] = zero;

    const unsigned short* Ab = &efT[(size_t)b * D_ * E_];
    const float* Hb = &H[(size_t)b * E_ * N_ + n0];

    uint4 ar0, ar1;
    float4 f0, f1, g0, g1;
    {   // prologue: ks=0 loads
        ar0 = *(const uint4*)&Ab[(size_t)r2 * E_ + cg * 8];
        ar1 = *(const uint4*)&Ab[(size_t)(r2 + 32) * E_ + cg * 8];
        const float* s0 = Hb + (size_t)(2 * r2) * N_ + cg * 8;
        const float* s1 = s0 + N_;
        f0 = *(const float4*)&s0[0]; f1 = *(const float4*)&s0[4];
        g0 = *(const float4*)&s1[0]; g1 = *(const float4*)&s1[4];
    }
    {   // write buf0
        *(uint4*)&aA[0][r2 * 72 + cg * 8] = ar0;
        *(uint4*)&aA[0][(r2 + 32) * 72 + cg * 8] = ar1;
        float r0a[8] = {f0.x, f0.y, f0.z, f0.w, f1.x, f1.y, f1.z, f1.w};
        float r1a[8] = {g0.x, g0.y, g0.z, g0.w, g1.x, g1.y, g1.z, g1.w};
        #pragma unroll
        for (int j = 0; j < 8; ++j)
            bB32[0][(cg * 8 + j) * 33 + r2] = pack2(r0a[j], r1a[j]);
    }
    __syncthreads();

    for (int ks = 0; ks < 16; ++ks) {
        if (ks < 15) {  // issue next-step loads before compute
            int k0 = (ks + 1) * 64;
            ar0 = *(const uint4*)&Ab[(size_t)r2 * E_ + k0 + cg * 8];
            ar1 = *(const uint4*)&Ab[(size_t)(r2 + 32) * E_ + k0 + cg * 8];
            const float* s0 = Hb + (size_t)(k0 + 2 * r2) * N_ + cg * 8;
            const float* s1 = s0 + N_;
            f0 = *(const float4*)&s0[0]; f1 = *(const float4*)&s0[4];
            g0 = *(const float4*)&s1[0]; g1 = *(const float4*)&s1[4];
        }
        int cur = ks & 1;
        #pragma unroll
        for (int hh = 0; hh < 2; ++hh) {
            union { unsigned int u[4]; bf16x8 v; } bb;
            #pragma unroll
            for (int i = 0; i < 4; ++i)
                bb.u[i] = bB32[cur][(w * 16 + c) * 33 + hh * 16 + q * 4 + i];
            #pragma unroll
            for (int fm = 0; fm < 4; ++fm) {
                bf16x8 afr = *(const bf16x8*)&aA[cur][(fm * 16 + c) * 72 + hh * 32 + q * 8];
                acc[fm] = MFMA16(afr, bb.v, acc[fm]);
            }
        }
        if (ks < 15) {
            int nxt = cur ^ 1;
            *(uint4*)&aA[nxt][r2 * 72 + cg * 8] = ar0;
            *(uint4*)&aA[nxt][(r2 + 32) * 72 + cg * 8] = ar1;
            float r0a[8] = {f0.x, f0.y, f0.z, f0.w, f1.x, f1.y, f1.z, f1.w};
            float r1a[8] = {g0.x, g0.y, g0.z, g0.w, g1.x, g1.y, g1.z, g1.w};
            #pragma unroll
            for (int j = 0; j < 8; ++j)
                bB32[nxt][(cg * 8 + j) * 33 + r2] = pack2(r0a[j], r1a[j]);
            __syncthreads();
        }
    }
    #pragma unroll
    for (int fm = 0; fm < 4; ++fm) {
        *(f32x4*)&out[((size_t)b * N_ + n0 + w * 16 + c) * 128 + fm * 16 + q * 4] = acc[fm];
    }
}

// ---------------------------------------------------------------------------
extern "C" void kernel_launch(void* const* d_in, const int* in_sizes, int n_in,
                              void* d_out, int out_size, void* d_ws, size_t ws_size,
                              hipStream_t stream) {
    const float* ed  = (const float*)d_in[0];  // [B,E,T]
    const float* H   = (const float*)d_in[1];  // [B,E,N]
    const float* ori = (const float*)d_in[2];  // [B,N,64]
    const float* W1  = (const float*)d_in[3];  // [T,64,128]
    const float* b1  = (const float*)d_in[4];  // [T,128]
    const float* W2  = (const float*)d_in[5];  // [T,128,64]
    const float* b2  = (const float*)d_in[6];  // [T,64]
    float* out = (float*)d_out;

    char* ws = (char*)d_ws;
    size_t used = 0;
    unsigned short* oriT = (unsigned short*)(ws + used); used += (size_t)B_ * D_ * N_ * 2;   // 4 MB
    unsigned short* W1T  = (unsigned short*)(ws + used); used += (size_t)T_ * HID_ * D_ * 2;
    unsigned short* W2T  = (unsigned short*)(ws + used); used += (size_t)T_ * D_ * HID_ * 2;
    unsigned short* efT  = (unsigned short*)(ws + used); used += (size_t)B_ * D_ * E_ * 2;   // 8 MB

    hipLaunchKernelGGL(k_prep_w, dim3(320), dim3(256), 0, stream, W1, W2, W1T, W2T);
    hipLaunchKernelGGL(k_ori_prep, dim3(8, 64), dim3(256), 0, stream, ori, out, oriT);
    hipLaunchKernelGGL(k_edge_mlp, dim3(1024), dim3(256), 0, stream,
                       H, oriT, ed, b1, b2, W1T, W2T, efT);
    hipLaunchKernelGGL(k_gemm_out, dim3(512), dim3(256), 0, stream, H, efT, out);
}